// Round 3
// baseline (4590.285 us; speedup 1.0000x reference)
//
#include <hip/hip_runtime.h>

// ---------------- QKV GEMM: qkv = x @ w_qkv, scatter to head layout --------
// M=8192, K=512, N=1536. Textbook 64x64 f32 tile, BK=32, 4x4 per thread.
__global__ __launch_bounds__(256) void s_qkv(
    const float* __restrict__ x, const float* __restrict__ w,
    float* __restrict__ q, float* __restrict__ k_, float* __restrict__ v_)
{
  __shared__ float As[64][33];
  __shared__ float Bs[32][65];
  const int tid = threadIdx.x;
  const int tx = tid & 15, ty = tid >> 4;
  const int m0 = blockIdx.x * 64, n0 = blockIdx.y * 64;
  float acc[4][4] = {};
  for (int k0 = 0; k0 < 512; k0 += 32) {
    __syncthreads();
#pragma unroll
    for (int i = 0; i < 8; ++i) {
      int e = tid + i * 256;            // 0..2047 = 64 rows x 32 k
      int r = e >> 5, c = e & 31;
      As[r][c] = x[(size_t)(m0 + r) * 512 + k0 + c];
    }
#pragma unroll
    for (int i = 0; i < 8; ++i) {
      int e = tid + i * 256;            // 0..2047 = 32 k x 64 n
      int r = e >> 6, c = e & 63;
      Bs[r][c] = w[(size_t)(k0 + r) * 1536 + n0 + c];
    }
    __syncthreads();
#pragma unroll
    for (int kk = 0; kk < 32; ++kk) {
      float a[4], b[4];
#pragma unroll
      for (int i = 0; i < 4; ++i) a[i] = As[ty * 4 + i][kk];
#pragma unroll
      for (int j = 0; j < 4; ++j) b[j] = Bs[kk][tx * 4 + j];
#pragma unroll
      for (int i = 0; i < 4; ++i)
#pragma unroll
        for (int j = 0; j < 4; ++j) acc[i][j] += a[i] * b[j];
    }
  }
  const int s = n0 >> 9;                // 0=q 1=k 2=val (n0 is 64-aligned)
  float* dst = (s == 0) ? q : (s == 1) ? k_ : v_;
#pragma unroll
  for (int i = 0; i < 4; ++i)
#pragma unroll
    for (int j = 0; j < 4; ++j) {
      int m = m0 + ty * 4 + i, n = n0 + tx * 4 + j;
      int b = m >> 10, v = m & 1023;
      int cc = n & 511, h = cc >> 6, d = cc & 63;
      dst[(((size_t)(b * 8 + h)) * 1024 + v) * 64 + d] = acc[i][j];
    }
}

// ---------------- attention: one block per (b,h,v) query row ---------------
__global__ __launch_bounds__(256) void s_attn(
    const float* __restrict__ q, const float* __restrict__ k_,
    const float* __restrict__ v_,
    const float* __restrict__ rpe_bias, const int* __restrict__ hop,
    float* __restrict__ attn, float* __restrict__ oh)
{
  __shared__ float qs[64];
  __shared__ float ps[1024];
  __shared__ float red[256];
  __shared__ float rpe[9];
  const int tid = threadIdx.x;
  const int bh = blockIdx.x >> 10, v = blockIdx.x & 1023;
  const int h = bh & 7, b = bh >> 3;
  if (tid < 64) qs[tid] = q[((size_t)bh * 1024 + v) * 64 + tid];
  if (tid >= 64 && tid < 73) rpe[tid - 64] = rpe_bias[h * 9 + (tid - 64)];
  __syncthreads();

  // scores for this query row
  const float* kb = k_ + (size_t)bh * 65536;
  const int* hr = hop + (size_t)v * 1024;
  for (int w = tid; w < 1024; w += 256) {
    const float* kr = kb + (size_t)w * 64;
    float s = 0.f;
#pragma unroll
    for (int d = 0; d < 64; d += 4) {
      float4 kv = *reinterpret_cast<const float4*>(kr + d);
      s += qs[d + 0] * kv.x;
      s += qs[d + 1] * kv.y;
      s += qs[d + 2] * kv.z;
      s += qs[d + 3] * kv.w;
    }
    ps[w] = (s + rpe[hr[w]]) * 0.125f;
  }
  __syncthreads();

  // block-wide max
  float m = -1e30f;
  for (int w = tid; w < 1024; w += 256) m = fmaxf(m, ps[w]);
  red[tid] = m;
  __syncthreads();
  for (int st = 128; st > 0; st >>= 1) {
    if (tid < st) red[tid] = fmaxf(red[tid], red[tid + st]);
    __syncthreads();
  }
  m = red[0];
  __syncthreads();

  // exp + block-wide sum
  float sum = 0.f;
  for (int w = tid; w < 1024; w += 256) { float e = __expf(ps[w] - m); ps[w] = e; sum += e; }
  red[tid] = sum;
  __syncthreads();
  for (int st = 128; st > 0; st >>= 1) {
    if (tid < st) red[tid] += red[tid + st];
    __syncthreads();
  }
  const float inv = 1.0f / red[0];
  __syncthreads();

  // normalize, write attn (f32)
  float* ar = attn + ((size_t)bh * 1024 + v) * 1024;
  for (int w = tid; w < 1024; w += 256) { float p = ps[w] * inv; ps[w] = p; ar[w] = p; }
  __syncthreads();

  // PV: thread (c = w-chunk, d): partial over 256 keys, then 4-way reduce
  const int d = tid & 63, c = tid >> 6;
  const float* vb = v_ + (size_t)bh * 65536;
  float acc = 0.f;
  for (int w = c * 256; w < c * 256 + 256; ++w)
    acc += ps[w] * vb[(size_t)w * 64 + d];
  red[tid] = acc;
  __syncthreads();
  if (c == 0) {
    float o = red[d] + red[64 + d] + red[128 + d] + red[192 + d];
    oh[((size_t)(b * 1024 + v)) * 512 + h * 64 + d] = o;
  }
}

// ---------------- output GEMM: out = oh @ w_out + b_out --------------------
__global__ __launch_bounds__(256) void s_out(
    const float* __restrict__ oh, const float* __restrict__ wo,
    const float* __restrict__ b_out, float* __restrict__ out)
{
  __shared__ float As[64][33];
  __shared__ float Bs[32][65];
  const int tid = threadIdx.x;
  const int tx = tid & 15, ty = tid >> 4;
  const int m0 = blockIdx.x * 64, n0 = blockIdx.y * 64;
  float acc[4][4] = {};
  for (int k0 = 0; k0 < 512; k0 += 32) {
    __syncthreads();
#pragma unroll
    for (int i = 0; i < 8; ++i) {
      int e = tid + i * 256;
      int r = e >> 5, c = e & 31;
      As[r][c] = oh[(size_t)(m0 + r) * 512 + k0 + c];
    }
#pragma unroll
    for (int i = 0; i < 8; ++i) {
      int e = tid + i * 256;
      int r = e >> 6, c = e & 63;
      Bs[r][c] = wo[(size_t)(k0 + r) * 512 + n0 + c];
    }
    __syncthreads();
#pragma unroll
    for (int kk = 0; kk < 32; ++kk) {
      float a[4], b[4];
#pragma unroll
      for (int i = 0; i < 4; ++i) a[i] = As[ty * 4 + i][kk];
#pragma unroll
      for (int j = 0; j < 4; ++j) b[j] = Bs[kk][tx * 4 + j];
#pragma unroll
      for (int i = 0; i < 4; ++i)
#pragma unroll
        for (int j = 0; j < 4; ++j) acc[i][j] += a[i] * b[j];
    }
  }
#pragma unroll
  for (int i = 0; i < 4; ++i)
#pragma unroll
    for (int j = 0; j < 4; ++j) {
      int m = m0 + ty * 4 + i, n = n0 + tx * 4 + j;
      out[(size_t)m * 512 + n] = acc[i][j] + b_out[n];
    }
}

extern "C" void kernel_launch(void* const* d_in, const int* in_sizes, int n_in,
                              void* d_out, int out_size, void* d_ws, size_t ws_size,
                              hipStream_t stream) {
  // Bind inputs BY SIZE (all six element counts are distinct) — immune to order.
  const float *x = nullptr, *w_qkv = nullptr, *w_out = nullptr,
              *b_out = nullptr, *rpe = nullptr;
  const int* hop = nullptr;
  for (int i = 0; i < n_in; ++i) {
    switch (in_sizes[i]) {
      case 4194304: x     = (const float*)d_in[i]; break;  // (8,1024,512)
      case 786432:  w_qkv = (const float*)d_in[i]; break;  // (512,1536)
      case 262144:  w_out = (const float*)d_in[i]; break;  // (512,512)
      case 512:     b_out = (const float*)d_in[i]; break;  // (512,)
      case 72:      rpe   = (const float*)d_in[i]; break;  // (8,9)
      case 1048576: hop   = (const int*)d_in[i];   break;  // (1024,1024) int32
    }
  }

  float* out  = (float*)d_out;                 // f32 outputs per reference dtype
  float* attn = out + (size_t)4194304;         // attn section (8,8,1024,1024)

  char* ws = (char*)d_ws;
  float* q_ = (float*)(ws);                    // 16 MB
  float* k_ = (float*)(ws + (size_t)16777216); // 16 MB
  float* v_ = (float*)(ws + (size_t)33554432); // 16 MB
  float* oh = (float*)(ws + (size_t)50331648); // 16 MB  (total 64 MB)

  s_qkv<<<dim3(128, 24), dim3(256), 0, stream>>>(x, w_qkv, q_, k_, v_);
  s_attn<<<dim3(65536), dim3(256), 0, stream>>>(q_, k_, v_, rpe, hop, attn, oh);
  s_out<<<dim3(128, 8), dim3(256), 0, stream>>>(oh, w_out, b_out, out);
}

// Round 4
// 228.480 us; speedup vs baseline: 20.0905x; 20.0905x over previous
//
#include <hip/hip_runtime.h>

typedef __attribute__((ext_vector_type(8))) short bf16x8;
typedef __attribute__((ext_vector_type(4))) float f32x4;

#define MFMA16(A,B,C) __builtin_amdgcn_mfma_f32_16x16x32_bf16(A,B,C,0,0,0)

__device__ __forceinline__ unsigned short f2bf(float f){
  unsigned int u = __float_as_uint(f);
  u += 0x7FFFu + ((u >> 16) & 1u);        // round-to-nearest-even
  return (unsigned short)(u >> 16);
}
__device__ __forceinline__ float bf2f(unsigned short s){
  return __uint_as_float(((unsigned int)s) << 16);
}
// byte offset into a [rows][64] bf16 LDS tile (128B rows), XOR-swizzled (G4)
__device__ __forceinline__ int swz(int row, int kbyte){
  return (row * 128 + kbyte) ^ ((row & 7) << 4);
}

// ---------------- prep: transpose weights to n-major bf16 ------------------
__global__ __launch_bounds__(256) void k_prep(
    const float* __restrict__ w_qkv, const float* __restrict__ w_out,
    unsigned short* __restrict__ wqT, unsigned short* __restrict__ woT)
{
  int idx = blockIdx.x * 256 + threadIdx.x;
  if (idx < 1536 * 512) {
    int n = idx >> 9, kq = idx & 511;
    wqT[idx] = f2bf(w_qkv[(size_t)kq * 1536 + n]);
  } else {
    int j = idx - 1536 * 512;                  // < 262144
    int n = j >> 9, kq = j & 511;
    woT[j] = f2bf(w_out[(size_t)kq * 512 + n]);
  }
}

// ---------------- QKV GEMM: qkv = x @ w_qkv (MFMA, bf16 in / f32 acc) ------
// M=8192, N=1536, K=512. Tile 128x128, BK=64, 4 waves (2x2 of 64x64).
__global__ __launch_bounds__(256) void k_qkv(
    const float* __restrict__ x, const unsigned short* __restrict__ wqT,
    unsigned short* __restrict__ q, unsigned short* __restrict__ k_,
    unsigned short* __restrict__ valT)
{
  __shared__ char lds[32768];
  char* At = lds; char* Bt = lds + 16384;
  const int tid = threadIdx.x;
  const int wid = tid >> 6, lane = tid & 63, g = lane >> 4, r = lane & 15;
  const int wm = wid >> 1, wn = wid & 1;
  const int m0 = blockIdx.x * 128, n0 = blockIdx.y * 128;

  f32x4 acc[4][4];
#pragma unroll
  for (int a = 0; a < 4; ++a)
#pragma unroll
    for (int b = 0; b < 4; ++b) acc[a][b] = (f32x4){0.f, 0.f, 0.f, 0.f};

  for (int kt = 0; kt < 8; ++kt) {
    const int k0 = kt * 64;
    __syncthreads();
    // stage A: x f32 -> bf16 tile (128 rows x 64 k)
#pragma unroll
    for (int it = 0; it < 8; ++it) {
      int c = tid + it * 256;            // 0..2047 = 128 rows x 16 chunks(4 f32)
      int row = c >> 4, c4 = c & 15;
      float4 xv = *reinterpret_cast<const float4*>(x + (size_t)(m0 + row) * 512 + k0 + c4 * 4);
      uint2 hv;
      hv.x = (unsigned)f2bf(xv.x) | ((unsigned)f2bf(xv.y) << 16);
      hv.y = (unsigned)f2bf(xv.z) | ((unsigned)f2bf(xv.w) << 16);
      *reinterpret_cast<uint2*>(At + swz(row, c4 * 8)) = hv;
    }
    // stage B: wqT (n-major) bf16
#pragma unroll
    for (int it = 0; it < 4; ++it) {
      int c = tid + it * 256;            // 0..1023 = 128 rows x 8 chunks(16B)
      int row = c >> 3, c8 = c & 7;
      *reinterpret_cast<uint4*>(Bt + swz(row, c8 * 16)) =
          *reinterpret_cast<const uint4*>(wqT + (size_t)(n0 + row) * 512 + k0 + c8 * 8);
    }
    __syncthreads();
#pragma unroll
    for (int kk = 0; kk < 2; ++kk) {
      bf16x8 af[4], bf[4];
      const int kb = (kk * 32 + 8 * g) * 2;
#pragma unroll
      for (int mi = 0; mi < 4; ++mi)
        af[mi] = *reinterpret_cast<const bf16x8*>(At + swz(wm * 64 + mi * 16 + r, kb));
#pragma unroll
      for (int ni = 0; ni < 4; ++ni)
        bf[ni] = *reinterpret_cast<const bf16x8*>(Bt + swz(wn * 64 + ni * 16 + r, kb));
#pragma unroll
      for (int mi = 0; mi < 4; ++mi)
#pragma unroll
        for (int ni = 0; ni < 4; ++ni)
          acc[mi][ni] = MFMA16(af[mi], bf[ni], acc[mi][ni]);
    }
  }
  // epilogue: scatter to q/k head layout or transposed valT
  const int s = n0 >> 9;  // 0=q 1=k 2=val (whole block in one section)
#pragma unroll
  for (int mi = 0; mi < 4; ++mi)
#pragma unroll
    for (int ni = 0; ni < 4; ++ni)
#pragma unroll
      for (int i = 0; i < 4; ++i) {
        int m = m0 + wm * 64 + mi * 16 + 4 * g + i;   // D row = 4g+i (m89)
        int n = n0 + wn * 64 + ni * 16 + r;           // D col = lane&15
        int b = m >> 10, v = m & 1023;
        int cc = n & 511, h = cc >> 6, d = cc & 63;
        int bh = b * 8 + h;
        unsigned short bfv = f2bf(acc[mi][ni][i]);
        if (s == 2)      valT[((size_t)bh * 64 + d) * 1024 + v] = bfv;
        else if (s == 0) q [((size_t)bh * 1024 + v) * 64 + d] = bfv;
        else             k_[((size_t)bh * 1024 + v) * 64 + d] = bfv;
      }
}

// ---------------- attention: scores + bias + softmax + attn + PV -----------
// One block = (b,h, 16 q-rows). 4 waves: wave w owns score cols [256w,256w+256),
// then softmax rows [4w,4w+4), then PV out cols [16w,16w+16).
__global__ __launch_bounds__(256) void k_attn(
    const unsigned short* __restrict__ q, const unsigned short* __restrict__ k_,
    const unsigned short* __restrict__ valT,
    const float* __restrict__ rpe_bias, const int* __restrict__ hop,
    float* __restrict__ attn, unsigned short* __restrict__ oh)
{
  __shared__ float S[16 * 1028];   // stride 1028 f32 (16B-aligned, bank-spread)
  __shared__ float rpe[9];
  const int tid = threadIdx.x;
  const int wid = tid >> 6, lane = tid & 63, g = lane >> 4, r = lane & 15;
  const int blk = blockIdx.x;
  const int vt = blk & 63, bh = blk >> 6, h = bh & 7;
  const int v0 = vt * 16;
  if (tid < 9) rpe[tid] = rpe_bias[h * 9 + tid];

  // Q fragments — registers (A-operand: row=r, k-slice 8g)
  const unsigned short* qp = q + ((size_t)bh * 1024 + v0) * 64;
  bf16x8 qf[2];
#pragma unroll
  for (int kk = 0; kk < 2; ++kk)
    qf[kk] = *reinterpret_cast<const bf16x8*>(qp + r * 64 + kk * 32 + 8 * g);
  __syncthreads();

  // scores: S[v][w] = (q.k + rpe[hop]) * 0.125  (K slab L2-resident, no staging)
  const unsigned short* kb = k_ + (size_t)bh * 65536;
  for (int ct = 0; ct < 16; ++ct) {
    int cb = wid * 256 + ct * 16;
    f32x4 acc = (f32x4){0.f, 0.f, 0.f, 0.f};
#pragma unroll
    for (int kk = 0; kk < 2; ++kk) {
      bf16x8 kf = *reinterpret_cast<const bf16x8*>(kb + (size_t)(cb + r) * 64 + kk * 32 + 8 * g);
      acc = MFMA16(qf[kk], kf, acc);
    }
    int wcol = cb + r;
#pragma unroll
    for (int i = 0; i < 4; ++i) {
      int vl = 4 * g + i;
      int hv = hop[(size_t)(v0 + vl) * 1024 + wcol];
      S[vl * 1028 + wcol] = (acc[i] + rpe[hv]) * 0.125f;
    }
  }
  __syncthreads();

  // wave-parallel softmax, 4 rows/wave; normalize in place + write f32 attn
#pragma unroll
  for (int rr = 0; rr < 4; ++rr) {
    int row = wid * 4 + rr;
    float* Sr = S + row * 1028;
    float e[16];
    float m = -1e30f;
#pragma unroll
    for (int j = 0; j < 16; ++j) { e[j] = Sr[lane + 64 * j]; m = fmaxf(m, e[j]); }
#pragma unroll
    for (int o = 32; o; o >>= 1) m = fmaxf(m, __shfl_xor(m, o, 64));
    float sum = 0.f;
#pragma unroll
    for (int j = 0; j < 16; ++j) { e[j] = __expf(e[j] - m); sum += e[j]; }
#pragma unroll
    for (int o = 32; o; o >>= 1) sum += __shfl_xor(sum, o, 64);
    float inv = 1.0f / sum;
    float* ar = attn + ((size_t)bh * 1024 + v0 + row) * 1024;
#pragma unroll
    for (int j = 0; j < 16; ++j) {
      float a = e[j] * inv;
      int col = lane + 64 * j;
      Sr[col] = a;
      ar[col] = a;           // coalesced 256B per j
    }
  }
  __syncthreads();

  // PV: out(16x64) = attn(16x1024) @ val(1024x64); wave owns 16 out cols
  const unsigned short* vT = valT + ((size_t)bh * 64 + wid * 16) * 1024;
  f32x4 acc = (f32x4){0.f, 0.f, 0.f, 0.f};
  for (int kc = 0; kc < 32; ++kc) {
    const float* ap = S + r * 1028 + kc * 32 + 8 * g;
    float4 p0 = *reinterpret_cast<const float4*>(ap);
    float4 p1 = *reinterpret_cast<const float4*>(ap + 4);
    bf16x8 af;
    af[0] = (short)f2bf(p0.x); af[1] = (short)f2bf(p0.y);
    af[2] = (short)f2bf(p0.z); af[3] = (short)f2bf(p0.w);
    af[4] = (short)f2bf(p1.x); af[5] = (short)f2bf(p1.y);
    af[6] = (short)f2bf(p1.z); af[7] = (short)f2bf(p1.w);
    bf16x8 bfr = *reinterpret_cast<const bf16x8*>(vT + (size_t)r * 1024 + kc * 32 + 8 * g);
    acc = MFMA16(af, bfr, acc);
  }
  const int b = bh >> 3;
#pragma unroll
  for (int i = 0; i < 4; ++i) {
    size_t oi = ((size_t)(b * 1024 + v0 + 4 * g + i)) * 512 + h * 64 + wid * 16 + r;
    oh[oi] = f2bf(acc[i]);
  }
}

// ---------------- output GEMM: out = oh @ w_out + b_out (f32 out) ----------
__global__ __launch_bounds__(256) void k_out(
    const unsigned short* __restrict__ oh, const unsigned short* __restrict__ woT,
    const float* __restrict__ b_out, float* __restrict__ out)
{
  __shared__ char lds[32768];
  char* At = lds; char* Bt = lds + 16384;
  const int tid = threadIdx.x;
  const int wid = tid >> 6, lane = tid & 63, g = lane >> 4, r = lane & 15;
  const int wm = wid >> 1, wn = wid & 1;
  const int m0 = blockIdx.x * 128, n0 = blockIdx.y * 128;

  f32x4 acc[4][4];
#pragma unroll
  for (int a = 0; a < 4; ++a)
#pragma unroll
    for (int b = 0; b < 4; ++b) acc[a][b] = (f32x4){0.f, 0.f, 0.f, 0.f};

  for (int kt = 0; kt < 8; ++kt) {
    const int k0 = kt * 64;
    __syncthreads();
#pragma unroll
    for (int it = 0; it < 4; ++it) {
      int c = tid + it * 256;
      int row = c >> 3, c8 = c & 7;
      *reinterpret_cast<uint4*>(At + swz(row, c8 * 16)) =
          *reinterpret_cast<const uint4*>(oh + (size_t)(m0 + row) * 512 + k0 + c8 * 8);
      *reinterpret_cast<uint4*>(Bt + swz(row, c8 * 16)) =
          *reinterpret_cast<const uint4*>(woT + (size_t)(n0 + row) * 512 + k0 + c8 * 8);
    }
    __syncthreads();
#pragma unroll
    for (int kk = 0; kk < 2; ++kk) {
      bf16x8 a4[4], b4[4];
      const int kb = (kk * 32 + 8 * g) * 2;
#pragma unroll
      for (int mi = 0; mi < 4; ++mi)
        a4[mi] = *reinterpret_cast<const bf16x8*>(At + swz(wm * 64 + mi * 16 + r, kb));
#pragma unroll
      for (int ni = 0; ni < 4; ++ni)
        b4[ni] = *reinterpret_cast<const bf16x8*>(Bt + swz(wn * 64 + ni * 16 + r, kb));
#pragma unroll
      for (int mi = 0; mi < 4; ++mi)
#pragma unroll
        for (int ni = 0; ni < 4; ++ni)
          acc[mi][ni] = MFMA16(a4[mi], b4[ni], acc[mi][ni]);
    }
  }
#pragma unroll
  for (int mi = 0; mi < 4; ++mi)
#pragma unroll
    for (int ni = 0; ni < 4; ++ni)
#pragma unroll
      for (int i = 0; i < 4; ++i) {
        int m = m0 + wm * 64 + mi * 16 + 4 * g + i;
        int n = n0 + wn * 64 + ni * 16 + r;
        out[(size_t)m * 512 + n] = acc[mi][ni][i] + b_out[n];
      }
}

extern "C" void kernel_launch(void* const* d_in, const int* in_sizes, int n_in,
                              void* d_out, int out_size, void* d_ws, size_t ws_size,
                              hipStream_t stream) {
  // Bind inputs BY SIZE (all six element counts distinct) — immune to order.
  const float *x = nullptr, *w_qkv = nullptr, *w_out = nullptr,
              *b_out = nullptr, *rpe = nullptr;
  const int* hop = nullptr;
  for (int i = 0; i < n_in; ++i) {
    switch (in_sizes[i]) {
      case 4194304: x     = (const float*)d_in[i]; break;  // (8,1024,512)
      case 786432:  w_qkv = (const float*)d_in[i]; break;  // (512,1536)
      case 262144:  w_out = (const float*)d_in[i]; break;  // (512,512)
      case 512:     b_out = (const float*)d_in[i]; break;  // (512,)
      case 72:      rpe   = (const float*)d_in[i]; break;  // (8,9)
      case 1048576: hop   = (const int*)d_in[i];   break;  // (1024,1024) int32
    }
  }

  float* out  = (float*)d_out;                 // f32 outputs
  float* attn = out + (size_t)4194304;         // attn section (8,8,1024,1024)

  char* ws = (char*)d_ws;
  unsigned short* q_   = (unsigned short*)(ws);                   // 8 MB
  unsigned short* k_   = (unsigned short*)(ws + (size_t) 8388608);// 8 MB
  unsigned short* valT = (unsigned short*)(ws + (size_t)16777216);// 8 MB
  unsigned short* oh   = (unsigned short*)(ws + (size_t)25165824);// 8 MB
  unsigned short* wqT  = (unsigned short*)(ws + (size_t)33554432);// 1.5 MB
  unsigned short* woT  = (unsigned short*)(ws + (size_t)35127296);// 0.5 MB
  // total ~35.6 MB of d_ws

  k_prep<<<dim3(4096), dim3(256), 0, stream>>>(w_qkv, w_out, wqT, woT);
  k_qkv<<<dim3(64, 12), dim3(256), 0, stream>>>(x, wqT, q_, k_, valT);
  k_attn<<<dim3(4096), dim3(256), 0, stream>>>(q_, k_, valT, rpe, hop, attn, oh);
  k_out<<<dim3(64, 4), dim3(256), 0, stream>>>(oh, woT, b_out, out);
}